// Round 1
// baseline (3181.732 us; speedup 1.0000x reference)
//
#include <hip/hip_runtime.h>
#include <math.h>

#define H 1024
#define SEQ 2048
#define BATCH 8
#define N_ENT 1000
#define TOPK 5
#define LN_EPS 1e-5f

// ---------- helpers ----------

__device__ __forceinline__ float gelu_erf(float x) {
    // exact (erf) GELU, matches jax.nn.gelu(approximate=False)
    return 0.5f * x * (1.0f + erff(x * 0.70710678118654752440f));
}

__device__ __forceinline__ float sigmoidf_(float x) {
    return 1.0f / (1.0f + expf(-x));
}

// block-wide sum; `red` is a 32-entry shared array. Safe to call repeatedly.
__device__ float block_sum(float v, float* red) {
    for (int off = 32; off > 0; off >>= 1) v += __shfl_down(v, off, 64);
    int wid = threadIdx.x >> 6;
    int lane = threadIdx.x & 63;
    int nw = blockDim.x >> 6;
    if (lane == 0) red[wid] = v;
    __syncthreads();
    if (threadIdx.x == 0) {
        float s = 0.f;
        for (int i = 0; i < nw; ++i) s += red[i];
        red[0] = s;
    }
    __syncthreads();
    float r = red[0];
    __syncthreads();
    return r;
}

// ---------- small kernels ----------

// pooled[b][h] = mean_s hs[b][s][h].  grid (H/256, BATCH), block 256
__global__ void pool_kernel(const float* __restrict__ hs, float* __restrict__ pooled) {
    int h = blockIdx.x * blockDim.x + threadIdx.x;
    int b = blockIdx.y;
    const float* p = hs + (size_t)b * SEQ * H + h;
    float acc = 0.f;
    for (int s = 0; s < SEQ; ++s) acc += p[(size_t)s * H];
    pooled[b * H + h] = acc * (1.0f / SEQ);
}

// relation encoder: H->H gelu -> H->H -> LN.  grid BATCH, block H(=1024)
__global__ void relation_kernel(const float* __restrict__ pooled,
                                const float* __restrict__ w1, const float* __restrict__ b1,
                                const float* __restrict__ w2, const float* __restrict__ b2,
                                const float* __restrict__ g, const float* __restrict__ beta,
                                float* __restrict__ out_rel) {
    __shared__ float x[H];
    __shared__ float h1[H];
    __shared__ float red[32];
    int b = blockIdx.x, t = threadIdx.x;
    x[t] = pooled[b * H + t];
    __syncthreads();
    float acc = b1[t];
    for (int k = 0; k < H; ++k) acc = fmaf(x[k], w1[k * H + t], acc);
    h1[t] = gelu_erf(acc);
    __syncthreads();
    float acc2 = b2[t];
    for (int k = 0; k < H; ++k) acc2 = fmaf(h1[k], w2[k * H + t], acc2);
    float mu = block_sum(acc2, red) * (1.0f / H);
    float d = acc2 - mu;
    float var = block_sum(d * d, red) * (1.0f / H);
    out_rel[b * H + t] = d * rsqrtf(var + LN_EPS) * g[t] + beta[t];
}

// sims[b][e] = dot(rel[b], ent[e]).  grid BATCH, block 256
__global__ void sim_kernel(const float* __restrict__ rel, const float* __restrict__ ent,
                           float* __restrict__ sims) {
    __shared__ float r[H];
    int b = blockIdx.x, t = threadIdx.x;
    for (int i = t; i < H; i += 256) r[i] = rel[b * H + i];
    __syncthreads();
    for (int e = t; e < N_ENT; e += 256) {
        const float* ep = ent + (size_t)e * H;
        float acc = 0.f;
        for (int k = 0; k < H; ++k) acc = fmaf(r[k], ep[k], acc);
        sims[b * N_ENT + e] = acc;
    }
}

// top-5 per batch row, serial argmax (first-occurrence tie-break like jax/np).
// grid 1, block 64 (threads 0..7 active)
__global__ void topk_kernel(const float* __restrict__ sims, float* __restrict__ out_idx_f,
                            int* __restrict__ idx_i) {
    int b = threadIdx.x;
    if (b >= BATCH) return;
    int sel[TOPK];
    for (int k = 0; k < TOPK; ++k) {
        float best = -INFINITY;
        int bi = 0;
        for (int e = 0; e < N_ENT; ++e) {
            bool skip = false;
            for (int j = 0; j < k; ++j) skip = skip || (sel[j] == e);
            float v = sims[b * N_ENT + e];
            if (!skip && v > best) { best = v; bi = e; }
        }
        sel[k] = bi;
        out_idx_f[b * TOPK + k] = (float)bi;
        idx_i[b * TOPK + k] = bi;
    }
}

// retrieved[b][k][:] = ent[idx[b][k]][:]; evec[b][:] = mean_k retrieved.
// grid BATCH, block H
__global__ void gather_kernel(const float* __restrict__ ent, const int* __restrict__ idx,
                              float* __restrict__ retrieved, float* __restrict__ evec) {
    int b = blockIdx.x, h = threadIdx.x;
    float acc = 0.f;
    for (int k = 0; k < TOPK; ++k) {
        float v = ent[(size_t)idx[b * TOPK + k] * H + h];
        retrieved[((size_t)b * TOPK + k) * H + h] = v;
        acc += v;
    }
    evec[b * H + h] = acc * (1.0f / TOPK);
}

// reasoning: [evec|rel|pooled] (3H) -> 2H gelu -> H -> LN.  grid BATCH, block H
__global__ void reasoning_kernel(const float* __restrict__ evec, const float* __restrict__ rel,
                                 const float* __restrict__ pooled,
                                 const float* __restrict__ w1, const float* __restrict__ b1,
                                 const float* __restrict__ w2, const float* __restrict__ b2,
                                 const float* __restrict__ g, const float* __restrict__ beta,
                                 float* __restrict__ out_ro) {
    __shared__ float xin[3 * H];
    __shared__ float h1[2 * H];
    __shared__ float red[32];
    int b = blockIdx.x, t = threadIdx.x;
    xin[t] = evec[b * H + t];
    xin[H + t] = rel[b * H + t];
    xin[2 * H + t] = pooled[b * H + t];
    __syncthreads();
    for (int jj = 0; jj < 2; ++jj) {
        int j = t + jj * H;
        float acc = b1[j];
        for (int k = 0; k < 3 * H; ++k) acc = fmaf(xin[k], w1[(size_t)k * 2 * H + j], acc);
        h1[j] = gelu_erf(acc);
    }
    __syncthreads();
    float acc2 = b2[t];
    for (int k = 0; k < 2 * H; ++k) acc2 = fmaf(h1[k], w2[k * H + t], acc2);
    float mu = block_sum(acc2, red) * (1.0f / H);
    float d = acc2 - mu;
    float var = block_sum(d * d, red) * (1.0f / H);
    out_ro[b * H + t] = d * rsqrtf(var + LN_EPS) * g[t] + beta[t];
}

// validation: H -> H/2 gelu -> 1 -> sigmoid.  grid BATCH, block 512
__global__ void validation_kernel(const float* __restrict__ ro,
                                  const float* __restrict__ w1, const float* __restrict__ b1,
                                  const float* __restrict__ w2, const float* __restrict__ b2,
                                  float* __restrict__ out_vs) {
    __shared__ float x[H];
    __shared__ float red[32];
    int b = blockIdx.x, t = threadIdx.x;
    x[t] = ro[b * H + t];
    x[t + 512] = ro[b * H + t + 512];
    __syncthreads();
    float acc = b1[t];
    for (int k = 0; k < H; ++k) acc = fmaf(x[k], w1[k * 512 + t], acc);
    float contrib = gelu_erf(acc) * w2[t];
    float s = block_sum(contrib, red);
    if (t == 0) out_vs[b] = sigmoidf_(s + b2[0]);
}

// ---------- big GEMM (entity encoder) ----------
// C[M,N] = act(A[M,K] @ W[K,N] + bias).  128x128 tile, BK=16, 256 thr, 8x8/thr.
template <int GELU>
__global__ __launch_bounds__(256) void gemm_kernel(const float* __restrict__ A,
                                                   const float* __restrict__ W,
                                                   const float* __restrict__ bias,
                                                   float* __restrict__ C,
                                                   int M, int N, int K) {
    __shared__ float As[16][132];  // padded: writes go As[k][m] with k fastest
    __shared__ float Bs[16][128];
    int m0 = blockIdx.y * 128, n0 = blockIdx.x * 128;
    int tm0 = (threadIdx.x >> 4) << 3;
    int tn0 = (threadIdx.x & 15) << 3;
    float acc[8][8] = {};
    for (int k0 = 0; k0 < K; k0 += 16) {
#pragma unroll
        for (int i = 0; i < 8; ++i) {
            int idx = threadIdx.x + i * 256;
            int m = idx >> 4, k = idx & 15;
            As[k][m] = A[(size_t)(m0 + m) * K + k0 + k];
        }
#pragma unroll
        for (int i = 0; i < 8; ++i) {
            int idx = threadIdx.x + i * 256;
            int kk = idx >> 7, n = idx & 127;
            Bs[kk][n] = W[(size_t)(k0 + kk) * N + n0 + n];
        }
        __syncthreads();
#pragma unroll
        for (int k = 0; k < 16; ++k) {
            float a[8], bb[8];
#pragma unroll
            for (int i = 0; i < 8; ++i) a[i] = As[k][tm0 + i];
#pragma unroll
            for (int i = 0; i < 8; ++i) bb[i] = Bs[k][tn0 + i];
#pragma unroll
            for (int i = 0; i < 8; ++i)
#pragma unroll
                for (int j = 0; j < 8; ++j) acc[i][j] = fmaf(a[i], bb[j], acc[i][j]);
        }
        __syncthreads();
    }
#pragma unroll
    for (int i = 0; i < 8; ++i) {
#pragma unroll
        for (int j = 0; j < 8; ++j) {
            float c = acc[i][j] + bias[n0 + tn0 + j];
            if (GELU) c = gelu_erf(c);
            C[(size_t)(m0 + tm0 + i) * N + n0 + tn0 + j] = c;
        }
    }
}

// per-row LayerNorm in place over entity_features. grid rows, block 256
__global__ void ln_rows_kernel(float* __restrict__ x, const float* __restrict__ g,
                               const float* __restrict__ beta) {
    __shared__ float red[32];
    float* p = x + (size_t)blockIdx.x * H;
    int t = threadIdx.x;
    float v[4];
#pragma unroll
    for (int i = 0; i < 4; ++i) v[i] = p[t + i * 256];
    float s = v[0] + v[1] + v[2] + v[3];
    float mu = block_sum(s, red) * (1.0f / H);
    float d2 = 0.f;
#pragma unroll
    for (int i = 0; i < 4; ++i) { float d = v[i] - mu; d2 += d * d; }
    float var = block_sum(d2, red) * (1.0f / H);
    float inv = rsqrtf(var + LN_EPS);
#pragma unroll
    for (int i = 0; i < 4; ++i)
        p[t + i * 256] = (v[i] - mu) * inv * g[t + i * 256] + beta[t + i * 256];
}

// ---------- launch ----------

extern "C" void kernel_launch(void* const* d_in, const int* in_sizes, int n_in,
                              void* d_out, int out_size, void* d_ws, size_t ws_size,
                              hipStream_t stream) {
    const float* hs     = (const float*)d_in[0];
    const float* ent    = (const float*)d_in[1];
    const float* ee_w1  = (const float*)d_in[2];
    const float* ee_b1  = (const float*)d_in[3];
    const float* ee_w2  = (const float*)d_in[4];
    const float* ee_b2  = (const float*)d_in[5];
    const float* ee_g   = (const float*)d_in[6];
    const float* ee_be  = (const float*)d_in[7];
    const float* re_w1  = (const float*)d_in[8];
    const float* re_b1  = (const float*)d_in[9];
    const float* re_w2  = (const float*)d_in[10];
    const float* re_b2  = (const float*)d_in[11];
    const float* re_g   = (const float*)d_in[12];
    const float* re_be  = (const float*)d_in[13];
    const float* rn_w1  = (const float*)d_in[14];
    const float* rn_b1  = (const float*)d_in[15];
    const float* rn_w2  = (const float*)d_in[16];
    const float* rn_b2  = (const float*)d_in[17];
    const float* rn_g   = (const float*)d_in[18];
    const float* rn_be  = (const float*)d_in[19];
    const float* vn_w1  = (const float*)d_in[20];
    const float* vn_b1  = (const float*)d_in[21];
    const float* vn_w2  = (const float*)d_in[22];
    const float* vn_b2  = (const float*)d_in[23];

    float* out = (float*)d_out;
    float* ef   = out;                                  // [8,2048,1024]
    float* rel  = ef + (size_t)BATCH * SEQ * H;         // [8,1024]
    float* retr = rel + BATCH * H;                      // [8,5,1024]
    float* sims = retr + BATCH * TOPK * H;              // [8,1000]
    float* tidx = sims + BATCH * N_ENT;                 // [8,5] as float
    float* ro   = tidx + BATCH * TOPK;                  // [8,1024]
    float* vs   = ro + BATCH * H;                       // [8,1]

    float* ws     = (float*)d_ws;
    float* pooled = ws;                 // 8192 floats
    float* evec   = ws + 8192;          // 8192 floats
    int*   idx_i  = (int*)(ws + 16384); // 40 ints
    float* scratch = ws + 32768;        // GEMM1 output staging

    // entity-branch row chunking based on available scratch
    long long scratch_f = ((long long)ws_size / 4) - 32768;
    int chunk = (int)(scratch_f / (2 * H));
    chunk &= ~127;
    if (chunk > BATCH * SEQ) chunk = BATCH * SEQ;
    if (chunk < 128) chunk = 128;

    // small path
    pool_kernel<<<dim3(H / 256, BATCH), 256, 0, stream>>>(hs, pooled);
    relation_kernel<<<BATCH, H, 0, stream>>>(pooled, re_w1, re_b1, re_w2, re_b2, re_g, re_be, rel);
    sim_kernel<<<BATCH, 256, 0, stream>>>(rel, ent, sims);
    topk_kernel<<<1, 64, 0, stream>>>(sims, tidx, idx_i);
    gather_kernel<<<BATCH, H, 0, stream>>>(ent, idx_i, retr, evec);
    reasoning_kernel<<<BATCH, H, 0, stream>>>(evec, rel, pooled, rn_w1, rn_b1, rn_w2, rn_b2,
                                              rn_g, rn_be, ro);
    validation_kernel<<<BATCH, 512, 0, stream>>>(ro, vn_w1, vn_b1, vn_w2, vn_b2, vs);

    // entity encoder (big)
    int total = BATCH * SEQ;
    for (int r0 = 0; r0 < total; r0 += chunk) {
        int m = total - r0;
        if (m > chunk) m = chunk;
        gemm_kernel<1><<<dim3(2 * H / 128, m / 128), 256, 0, stream>>>(
            hs + (size_t)r0 * H, ee_w1, ee_b1, scratch, m, 2 * H, H);
        gemm_kernel<0><<<dim3(H / 128, m / 128), 256, 0, stream>>>(
            scratch, ee_w2, ee_b2, ef + (size_t)r0 * H, m, H, 2 * H);
    }
    ln_rows_kernel<<<total, 256, 0, stream>>>(ef, ee_g, ee_be);
}

// Round 2
// 600.199 us; speedup vs baseline: 5.3011x; 5.3011x over previous
//
#include <hip/hip_runtime.h>
#include <math.h>

#define H 1024
#define SEQ 2048
#define BATCH 8
#define N_ENT 1000
#define TOPK 5
#define LN_EPS 1e-5f

using bf16x8 = __attribute__((ext_vector_type(8))) __bf16;
using f32x4  = __attribute__((ext_vector_type(4))) float;
#define AS1 __attribute__((address_space(1)))
#define AS3 __attribute__((address_space(3)))

// ---------- helpers ----------

__device__ __forceinline__ float gelu_erf(float x) {
    return 0.5f * x * (1.0f + erff(x * 0.70710678118654752440f));
}

__device__ __forceinline__ float sigmoidf_(float x) {
    return 1.0f / (1.0f + expf(-x));
}

__device__ __forceinline__ unsigned short f2bf(float f) {
    unsigned int u = __float_as_uint(f);
    unsigned int r = (u + 0x7fffu + ((u >> 16) & 1u)) >> 16;  // round-nearest-even
    return (unsigned short)r;
}

__device__ float block_sum(float v, float* red) {
    for (int off = 32; off > 0; off >>= 1) v += __shfl_down(v, off, 64);
    int wid = threadIdx.x >> 6;
    int lane = threadIdx.x & 63;
    int nw = blockDim.x >> 6;
    if (lane == 0) red[wid] = v;
    __syncthreads();
    if (threadIdx.x == 0) {
        float s = 0.f;
        for (int i = 0; i < nw; ++i) s += red[i];
        red[0] = s;
    }
    __syncthreads();
    float r = red[0];
    __syncthreads();
    return r;
}

// ---------- conversion kernels ----------

// flat fp32 -> bf16, 4 elems/thread
__global__ void f2bf_kernel(const float* __restrict__ in, unsigned short* __restrict__ out, int n) {
    int i = (blockIdx.x * blockDim.x + threadIdx.x) * 4;
    if (i >= n) return;
    float4 v = *(const float4*)(in + i);
    ushort4 o;
    o.x = f2bf(v.x); o.y = f2bf(v.y); o.z = f2bf(v.z); o.w = f2bf(v.w);
    *(ushort4*)(out + i) = o;
}

// in [R][C] fp32 -> out [C][R] bf16 (tiled transpose)
__global__ void transpose_bf_kernel(const float* __restrict__ in, unsigned short* __restrict__ out,
                                    int R, int C) {
    __shared__ float tile[32][33];
    int c0 = blockIdx.x * 32, r0 = blockIdx.y * 32;
    int tx = threadIdx.x & 31, ty = threadIdx.x >> 5;  // ty 0..7
#pragma unroll
    for (int i = 0; i < 32; i += 8)
        tile[ty + i][tx] = in[(size_t)(r0 + ty + i) * C + c0 + tx];
    __syncthreads();
#pragma unroll
    for (int i = 0; i < 32; i += 8)
        out[(size_t)(c0 + ty + i) * R + r0 + tx] = f2bf(tile[tx][ty + i]);
}

// ---------- pooling (2-phase) ----------

// grid (32 s-chunks, 8 b), block 256: partial[b][sc][h]
__global__ void pool1_kernel(const float* __restrict__ hs, float* __restrict__ part) {
    int sc = blockIdx.x, b = blockIdx.y, t = threadIdx.x;
    float a0 = 0, a1 = 0, a2 = 0, a3 = 0;
    const float* p = hs + ((size_t)b * SEQ + sc * 64) * H;
    for (int s = 0; s < 64; ++s) {
        const float* q = p + (size_t)s * H;
        a0 += q[t]; a1 += q[t + 256]; a2 += q[t + 512]; a3 += q[t + 768];
    }
    float* o = part + ((size_t)b * 32 + sc) * H;
    o[t] = a0; o[t + 256] = a1; o[t + 512] = a2; o[t + 768] = a3;
}

__global__ void pool2_kernel(const float* __restrict__ part, float* __restrict__ pooled) {
    int b = blockIdx.x, t = threadIdx.x;
    for (int c = 0; c < 4; ++c) {
        float s = 0.f;
        for (int sc = 0; sc < 32; ++sc) s += part[((size_t)b * 32 + sc) * H + t + c * 256];
        pooled[b * H + t + c * 256] = s * (1.0f / SEQ);
    }
}

// ---------- small MLP path: k-split partial + reduce ----------

// partial[ks][b][j] = sum_{k in ks-range} X[b][k] * W[k][j]
// grid (N/256, K/KRANGE), block 256
template <int KRANGE>
__global__ void mlp_partial_kernel(const float* __restrict__ X, int ldx,
                                   const float* __restrict__ W, int N,
                                   float* __restrict__ part) {
    __shared__ float xs[8][KRANGE];
    int jb = blockIdx.x, ks = blockIdx.y, t = threadIdx.x;
    int k0 = ks * KRANGE;
    for (int i = t; i < 8 * KRANGE; i += 256) {
        int b = i / KRANGE, k = i % KRANGE;
        xs[b][k] = X[(size_t)b * ldx + k0 + k];
    }
    __syncthreads();
    int j = jb * 256 + t;
    float acc[8] = {};
    for (int k = 0; k < KRANGE; ++k) {
        float w = W[(size_t)(k0 + k) * N + j];
#pragma unroll
        for (int b = 0; b < 8; ++b) acc[b] = fmaf(xs[b][k], w, acc[b]);
    }
#pragma unroll
    for (int b = 0; b < 8; ++b) part[((size_t)ks * 8 + b) * N + j] = acc[b];
}

// out[b][j] = gelu( sum_ks part + bias[j] ).  grid (N/256, 8), block 256
__global__ void mlp_reduce_gelu_kernel(const float* __restrict__ part, const float* __restrict__ bias,
                                       float* __restrict__ out, int N, int nks) {
    int b = blockIdx.y;
    int j = blockIdx.x * 256 + threadIdx.x;
    float s = bias[j];
    for (int ks = 0; ks < nks; ++ks) s += part[((size_t)ks * 8 + b) * N + j];
    out[(size_t)b * N + j] = gelu_erf(s);
}

// out[b][:] = LN( sum_ks part + bias ).  grid 8, block 1024 (N == H)
__global__ void mlp_reduce_ln_kernel(const float* __restrict__ part, const float* __restrict__ bias,
                                     const float* __restrict__ g, const float* __restrict__ be,
                                     float* __restrict__ out, int nks) {
    __shared__ float red[32];
    int b = blockIdx.x, t = threadIdx.x;
    float s = bias[t];
    for (int ks = 0; ks < nks; ++ks) s += part[((size_t)ks * 8 + b) * H + t];
    float mu = block_sum(s, red) * (1.0f / H);
    float d = s - mu;
    float var = block_sum(d * d, red) * (1.0f / H);
    out[(size_t)b * H + t] = d * rsqrtf(var + LN_EPS) * g[t] + be[t];
}

// ---------- sims / topk / gather / concat ----------

// one wave per entity; all 8 batches per wave.  grid 250, block 256
__global__ void sim_kernel(const float* __restrict__ rel, const float* __restrict__ ent,
                           float* __restrict__ sims) {
    __shared__ float rl[8 * H];
    int t = threadIdx.x;
    for (int i = t; i < 8 * H; i += 256) rl[i] = rel[i];
    __syncthreads();
    int e = blockIdx.x * 4 + (t >> 6);
    int lane = t & 63;
    float ev[16];
    const float* ep = ent + (size_t)e * H;
#pragma unroll
    for (int i = 0; i < 16; ++i) ev[i] = ep[lane + i * 64];
#pragma unroll
    for (int b = 0; b < 8; ++b) {
        float a = 0.f;
#pragma unroll
        for (int i = 0; i < 16; ++i) a = fmaf(ev[i], rl[b * H + lane + i * 64], a);
        for (int off = 32; off > 0; off >>= 1) a += __shfl_down(a, off, 64);
        if (lane == 0) sims[b * N_ENT + e] = a;
    }
}

// exact top-5, first-index tie-break.  grid 8, block 256
__global__ void topk_kernel(const float* __restrict__ sims, float* __restrict__ out_idx_f,
                            int* __restrict__ idx_i) {
    __shared__ float v[1024];
    __shared__ float rv[4];
    __shared__ int ri[4];
    int b = blockIdx.x, t = threadIdx.x;
    for (int i = t; i < 1024; i += 256) v[i] = (i < N_ENT) ? sims[b * N_ENT + i] : -INFINITY;
    __syncthreads();
    for (int k = 0; k < TOPK; ++k) {
        float best = -INFINITY;
        int bi = 0x7fffffff;
        for (int i = t; i < 1024; i += 256) {
            float x = v[i];
            if (x > best || (x == best && i < bi)) { best = x; bi = i; }
        }
        for (int off = 32; off > 0; off >>= 1) {
            float ov = __shfl_down(best, off, 64);
            int oi = __shfl_down(bi, off, 64);
            if (ov > best || (ov == best && oi < bi)) { best = ov; bi = oi; }
        }
        if ((t & 63) == 0) { rv[t >> 6] = best; ri[t >> 6] = bi; }
        __syncthreads();
        if (t == 0) {
            for (int w = 1; w < 4; ++w)
                if (rv[w] > rv[0] || (rv[w] == rv[0] && ri[w] < ri[0])) { rv[0] = rv[w]; ri[0] = ri[w]; }
            int sel = ri[0];
            out_idx_f[b * TOPK + k] = (float)sel;
            idx_i[b * TOPK + k] = sel;
            v[sel] = -INFINITY;
        }
        __syncthreads();
    }
}

// grid 8, block 1024
__global__ void gather_kernel(const float* __restrict__ ent, const int* __restrict__ idx,
                              float* __restrict__ retrieved, float* __restrict__ evec) {
    int b = blockIdx.x, h = threadIdx.x;
    float acc = 0.f;
    for (int k = 0; k < TOPK; ++k) {
        float v = ent[(size_t)idx[b * TOPK + k] * H + h];
        retrieved[((size_t)b * TOPK + k) * H + h] = v;
        acc += v;
    }
    evec[b * H + h] = acc * (1.0f / TOPK);
}

// grid 8, block 1024
__global__ void concat_kernel(const float* __restrict__ evec, const float* __restrict__ rel,
                              const float* __restrict__ pooled, float* __restrict__ xin) {
    int b = blockIdx.x, t = threadIdx.x;
    xin[(size_t)b * 3 * H + t] = evec[b * H + t];
    xin[(size_t)b * 3 * H + H + t] = rel[b * H + t];
    xin[(size_t)b * 3 * H + 2 * H + t] = pooled[b * H + t];
}

// validation final: gelu + dot + sigmoid.  grid 8, block 512
__global__ void vn_final_kernel(const float* __restrict__ part, const float* __restrict__ b1,
                                const float* __restrict__ w2, const float* __restrict__ b2,
                                float* __restrict__ vs, int nks) {
    __shared__ float red[32];
    int b = blockIdx.x, t = threadIdx.x;
    float s = b1[t];
    for (int ks = 0; ks < nks; ++ks) s += part[((size_t)ks * 8 + b) * 512 + t];
    float c = gelu_erf(s) * w2[t];
    float tot = block_sum(c, red);
    if (t == 0) vs[b] = sigmoidf_(tot + b2[0]);
}

// ---------- bf16 MFMA GEMM (m97 structure) ----------
// C[M,N] = epi(A[M,K]_bf16 @ Bt[N,K]_bf16^T + bias)
// 128x128 tile, BK=32, 4 waves (2x2), each wave 64x64 via 4x4 of 16x16x32 MFMA.
template <int GELU_BF16_OUT>
__global__ __launch_bounds__(256) void gemm_mfma(const unsigned short* __restrict__ A,
                                                 const unsigned short* __restrict__ Bt,
                                                 const float* __restrict__ bias,
                                                 void* __restrict__ Cout,
                                                 int M, int N, int K) {
    __shared__ __align__(16) unsigned short As[128 * 32];
    __shared__ __align__(16) unsigned short Bs[128 * 32];
    const int tid = threadIdx.x;
    const int lane = tid & 63;
    const int m0 = blockIdx.y * 128, n0 = blockIdx.x * 128;
    const int wave = tid >> 6;
    const int wm = (wave >> 1) * 64, wn = (wave & 1) * 64;

    const int rowA_f = wm + (lane & 15);
    const int rowB_f = wn + (lane & 15);
    const int kq = (lane >> 4) * 8;

    f32x4 acc[4][4] = {};

    for (int k0 = 0; k0 < K; k0 += 32) {
        // stage A and B tiles: 2 rounds x 256 lanes x 16B each
#pragma unroll
        for (int r = 0; r < 2; ++r) {
            int e = (r * 256 + tid) * 8;      // bf16 element index in tile
            int row = e >> 5, kk = e & 31;    // [row][k] row-major, BK=32
            const unsigned short* ga = A + (size_t)(m0 + row) * K + k0 + kk;
            const unsigned short* gb = Bt + (size_t)(n0 + row) * K + k0 + kk;
            unsigned short* la = As + (size_t)(r * 256 + (tid & ~63)) * 8;  // wave-uniform base
            unsigned short* lb = Bs + (size_t)(r * 256 + (tid & ~63)) * 8;
            __builtin_amdgcn_global_load_lds((AS1 void*)ga, (AS3 void*)la, 16, 0, 0);
            __builtin_amdgcn_global_load_lds((AS1 void*)gb, (AS3 void*)lb, 16, 0, 0);
        }
        __syncthreads();
        bf16x8 af[4], bfg[4];
#pragma unroll
        for (int i = 0; i < 4; ++i)
            af[i] = *(const bf16x8*)(As + (rowA_f + i * 16) * 32 + kq);
#pragma unroll
        for (int j = 0; j < 4; ++j)
            bfg[j] = *(const bf16x8*)(Bs + (rowB_f + j * 16) * 32 + kq);
#pragma unroll
        for (int i = 0; i < 4; ++i)
#pragma unroll
            for (int j = 0; j < 4; ++j)
                acc[i][j] = __builtin_amdgcn_mfma_f32_16x16x32_bf16(af[i], bfg[j], acc[i][j], 0, 0, 0);
        __syncthreads();
    }

    // epilogue: C/D layout col=lane&15, row=(lane>>4)*4+r  [verified m89]
    const int cn = lane & 15;
    const int rbase = (lane >> 4) * 4;
#pragma unroll
    for (int i = 0; i < 4; ++i) {
#pragma unroll
        for (int j = 0; j < 4; ++j) {
            int n = n0 + wn + j * 16 + cn;
            float bv = bias[n];
            int mb = m0 + wm + i * 16 + rbase;
#pragma unroll
            for (int r = 0; r < 4; ++r) {
                float c = acc[i][j][r] + bv;
                if (GELU_BF16_OUT) {
                    c = gelu_erf(c);
                    ((unsigned short*)Cout)[(size_t)(mb + r) * N + n] = f2bf(c);
                } else {
                    ((float*)Cout)[(size_t)(mb + r) * N + n] = c;
                }
            }
        }
    }
}

// per-row LayerNorm in place. grid rows, block 256
__global__ void ln_rows_kernel(float* __restrict__ x, const float* __restrict__ g,
                               const float* __restrict__ beta) {
    __shared__ float red[32];
    float* p = x + (size_t)blockIdx.x * H;
    int t = threadIdx.x;
    float v[4];
#pragma unroll
    for (int i = 0; i < 4; ++i) v[i] = p[t + i * 256];
    float s = v[0] + v[1] + v[2] + v[3];
    float mu = block_sum(s, red) * (1.0f / H);
    float d2 = 0.f;
#pragma unroll
    for (int i = 0; i < 4; ++i) { float d = v[i] - mu; d2 += d * d; }
    float var = block_sum(d2, red) * (1.0f / H);
    float inv = rsqrtf(var + LN_EPS);
#pragma unroll
    for (int i = 0; i < 4; ++i)
        p[t + i * 256] = (v[i] - mu) * inv * g[t + i * 256] + beta[t + i * 256];
}

// ---------- launch ----------

extern "C" void kernel_launch(void* const* d_in, const int* in_sizes, int n_in,
                              void* d_out, int out_size, void* d_ws, size_t ws_size,
                              hipStream_t stream) {
    const float* hs     = (const float*)d_in[0];
    const float* ent    = (const float*)d_in[1];
    const float* ee_w1  = (const float*)d_in[2];
    const float* ee_b1  = (const float*)d_in[3];
    const float* ee_w2  = (const float*)d_in[4];
    const float* ee_b2  = (const float*)d_in[5];
    const float* ee_g   = (const float*)d_in[6];
    const float* ee_be  = (const float*)d_in[7];
    const float* re_w1  = (const float*)d_in[8];
    const float* re_b1  = (const float*)d_in[9];
    const float* re_w2  = (const float*)d_in[10];
    const float* re_b2  = (const float*)d_in[11];
    const float* re_g   = (const float*)d_in[12];
    const float* re_be  = (const float*)d_in[13];
    const float* rn_w1  = (const float*)d_in[14];
    const float* rn_b1  = (const float*)d_in[15];
    const float* rn_w2  = (const float*)d_in[16];
    const float* rn_b2  = (const float*)d_in[17];
    const float* rn_g   = (const float*)d_in[18];
    const float* rn_be  = (const float*)d_in[19];
    const float* vn_w1  = (const float*)d_in[20];
    const float* vn_b1  = (const float*)d_in[21];
    const float* vn_w2  = (const float*)d_in[22];
    const float* vn_b2  = (const float*)d_in[23];

    float* out = (float*)d_out;
    float* ef   = out;                                  // [8,2048,1024]
    float* rel  = ef + (size_t)BATCH * SEQ * H;         // [8,1024]
    float* retr = rel + BATCH * H;                      // [8,5,1024]
    float* sims = retr + BATCH * TOPK * H;              // [8,1000]
    float* tidx = sims + BATCH * N_ENT;                 // [8,5] as float
    float* ro   = tidx + BATCH * TOPK;                  // [8,1024]
    float* vs   = ro + BATCH * H;                       // [8,1]

    // ---- workspace layout (floats) ----
    float* ws = (float*)d_ws;
    size_t o = 0;
    float* pooled = ws + o; o += 8192;
    float* evec   = ws + o; o += 8192;
    int*   idx_i  = (int*)(ws + o); o += 64;
    float* xin    = ws + o; o += 8 * 3 * H;     // 24576
    float* h1r    = ws + o; o += 8 * H;         // 8192
    float* h1n    = ws + o; o += 8 * 2 * H;     // 16384
    float* part   = ws + o; o += 24 * 8 * 2048; // 393216, reused by all partial stages
    unsigned short* w1t = (unsigned short*)(ws + o); o += (2048 * 1024) / 2;
    unsigned short* w2t = (unsigned short*)(ws + o); o += (2048 * 1024) / 2;
    unsigned short* hsb = (unsigned short*)(ws + o);

    long long avail = (long long)(ws_size / 4) - (long long)o;  // floats left
    int chunk = (int)(avail / 1536);  // per row: 1024 + 2048 bf16 = 1536 floats
    chunk &= ~127;
    if (chunk > BATCH * SEQ) chunk = BATCH * SEQ;
    if (chunk < 128) chunk = 128;
    unsigned short* midb = hsb + (size_t)chunk * H;

    // ---- weight prep ----
    transpose_bf_kernel<<<dim3(2048 / 32, 1024 / 32), 256, 0, stream>>>(ee_w1, w1t, 1024, 2048);
    transpose_bf_kernel<<<dim3(1024 / 32, 2048 / 32), 256, 0, stream>>>(ee_w2, w2t, 2048, 1024);

    // ---- small path ----
    pool1_kernel<<<dim3(32, BATCH), 256, 0, stream>>>(hs, part);
    pool2_kernel<<<BATCH, 256, 0, stream>>>(part, pooled);

    mlp_partial_kernel<64><<<dim3(4, 16), 256, 0, stream>>>(pooled, H, re_w1, H, part);
    mlp_reduce_gelu_kernel<<<dim3(4, 8), 256, 0, stream>>>(part, re_b1, h1r, H, 16);
    mlp_partial_kernel<64><<<dim3(4, 16), 256, 0, stream>>>(h1r, H, re_w2, H, part);
    mlp_reduce_ln_kernel<<<BATCH, 1024, 0, stream>>>(part, re_b2, re_g, re_be, rel, 16);

    sim_kernel<<<250, 256, 0, stream>>>(rel, ent, sims);
    topk_kernel<<<BATCH, 256, 0, stream>>>(sims, tidx, idx_i);
    gather_kernel<<<BATCH, 1024, 0, stream>>>(ent, idx_i, retr, evec);
    concat_kernel<<<BATCH, 1024, 0, stream>>>(evec, rel, pooled, xin);

    mlp_partial_kernel<128><<<dim3(8, 24), 256, 0, stream>>>(xin, 3 * H, rn_w1, 2 * H, part);
    mlp_reduce_gelu_kernel<<<dim3(8, 8), 256, 0, stream>>>(part, rn_b1, h1n, 2 * H, 24);
    mlp_partial_kernel<128><<<dim3(4, 16), 256, 0, stream>>>(h1n, 2 * H, rn_w2, H, part);
    mlp_reduce_ln_kernel<<<BATCH, 1024, 0, stream>>>(part, rn_b2, rn_g, rn_be, ro, 16);

    mlp_partial_kernel<128><<<dim3(2, 8), 256, 0, stream>>>(ro, H, vn_w1, 512, part);
    vn_final_kernel<<<BATCH, 512, 0, stream>>>(part, vn_b1, vn_w2, vn_b2, vs, 8);

    // ---- entity encoder (bf16 MFMA) ----
    int total = BATCH * SEQ;
    for (int r0 = 0; r0 < total; r0 += chunk) {
        int m = total - r0;
        if (m > chunk) m = chunk;
        int nconv = m * H;
        f2bf_kernel<<<(nconv / 4 + 255) / 256, 256, 0, stream>>>(hs + (size_t)r0 * H, hsb, nconv);
        gemm_mfma<1><<<dim3(2048 / 128, m / 128), 256, 0, stream>>>(hsb, w1t, ee_b1, midb,
                                                                    m, 2048, 1024);
        gemm_mfma<0><<<dim3(1024 / 128, m / 128), 256, 0, stream>>>(midb, w2t, ee_b2,
                                                                    ef + (size_t)r0 * H,
                                                                    m, 1024, 2048);
    }
    ln_rows_kernel<<<total, 256, 0, stream>>>(ef, ee_g, ee_be);
}